// Round 4
// baseline (1019.935 us; speedup 1.0000x reference)
//
#include <hip/hip_runtime.h>

// 2-layer LSTM (PyTorch gate order i,f,g,o), L=2048, B=512, INPUT=78, H=4.
//
// R9: SINGLE fused kernel. 256 blocks x 320 threads (5 waves):
//   wave 0  = consumer: the R6-proven recurrence (measured 259-261us), 16
//             lanes per (batch,layer), one gate per lane, 4 trans ops/step,
//             quad_perm gate gather, 7 ds_swizzle XORs, prefetch depth 8.
//   waves 1-4 = producers: compute this block's OWN xg slice (2 batches x
//             2048 t x 16 gates) on the 3 otherwise-idle SIMDs, hidden under
//             the consumer's latency-bound 260us. Per lane: one (t,b,row)
//             dot-78, weights prescaled in 78 VGPRs, x via 16-lane-broadcast
//             global loads (L1-absorbed), 4-way split accumulators.
//             Wave w pass p covers t = 8p + 2(w-1) + {0,1}.
//   Handoff: block-local only (same CU/XCD -> no coherence exposure).
//     producer: stores -> __threadfence_block() -> LDS watermark (own u16).
//     consumer: avail = 8*min(4 watermarks), polled once per 8-step window
//     (ds_read_b64, uniform; short-circuits once avail==2048). Prefetch of
//     xg[t] strictly gated behind avail > t => first-touch after produce.
//   Layer-1 bias now a per-lane constant folded via base = keep*buf + badd
//   (ws bias slot retired). Deadlock-free: producers/consumer co-resident by
//   block construction; single __syncthreads only at init (all waves).
//
// ws: [20480 B, 20480+64MiB) xg0[t][b][j*4+g], prescaled by +-log2e.

#define LSEQ  2048
#define BATCH 512
#define NIN   78
#define LOG2E 1.4426950408889634f

#define WS_XG_F    5120
#define XG_BYTES   ((unsigned)LSEQ * BATCH * 16u * 4u)

__device__ __forceinline__ float rcp_(float x) { return __builtin_amdgcn_rcpf(x); }
__device__ __forceinline__ float ex2_(float x) { return __builtin_amdgcn_exp2f(x); }

template<int CTRL>
__device__ __forceinline__ float dppf(float x) {
  int r = __builtin_amdgcn_update_dpp(0, __builtin_bit_cast(int, x), CTRL, 0xf, 0xf, false);
  return __builtin_bit_cast(float, r);
}
template<int PAT>
__device__ __forceinline__ float swzf(float x) {
  int r = __builtin_amdgcn_ds_swizzle(__builtin_bit_cast(int, x), PAT);
  return __builtin_bit_cast(float, r);
}

__global__ __launch_bounds__(320) void lstm_fused(
    const float* __restrict__ x,
    const int* __restrict__ lens,
    const float* __restrict__ Wih0, const float* __restrict__ Whh0,
    const float* __restrict__ bih0, const float* __restrict__ bhh0,
    const float* __restrict__ Wih1, const float* __restrict__ Whh1,
    const float* __restrict__ bih1, const float* __restrict__ bhh1,
    float* __restrict__ ws, float* __restrict__ out)
{
  __shared__ unsigned long long progq;   // 4 x u16 producer watermarks
  const int tid  = threadIdx.x;
  const int wave = tid >> 6;
  const int lane = tid & 63;
  if (tid == 0) progq = 0ull;
  __syncthreads();                       // only barrier in the kernel
  const int b0 = blockIdx.x * 2;

  if (wave != 0) {
    // ---------------- producers (waves 1..4) ----------------
    const int w   = wave;                // 1..4
    const int a   = lane & 15;           // output index j*4+g
    const int grp = lane >> 4;
    const int dt  = grp >> 1, db = grp & 1;
    const int j   = a >> 2, g = a & 3;
    const float s = (g == 2) ? 2.f * LOG2E : -LOG2E;
    const int row = g * 4 + j;           // PyTorch row = gate*4 + unit

    float wr[NIN];                       // prescaled weight row in VGPRs
#pragma unroll
    for (int k = 0; k < NIN; ++k) wr[k] = s * Wih0[row * NIN + k];
    const float bias0 = s * (bih0[row] + bhh0[row]);

    const int b = b0 + db;
    float* __restrict__ xg = ws + WS_XG_F;
    volatile unsigned short* pr = (volatile unsigned short*)&progq;

    for (int p = 0; p < LSEQ / 8; ++p) {
      const int t = 8 * p + 2 * (w - 1) + dt;
      const float* __restrict__ xr = x + ((size_t)t * BATCH + b) * NIN;
      float a0 = bias0, a1 = 0.f, a2 = 0.f, a3 = 0.f;
#pragma unroll
      for (int k = 0; k < 76; k += 4) {
        a0 = fmaf(xr[k],     wr[k],     a0);
        a1 = fmaf(xr[k + 1], wr[k + 1], a1);
        a2 = fmaf(xr[k + 2], wr[k + 2], a2);
        a3 = fmaf(xr[k + 3], wr[k + 3], a3);
      }
      a0 = fmaf(xr[76], wr[76], a0);
      a1 = fmaf(xr[77], wr[77], a1);
      xg[((size_t)t * BATCH + b) * 16 + a] = (a0 + a1) + (a2 + a3);
      __threadfence_block();             // drain stores before signaling
      if (lane == 0) pr[w - 1] = (unsigned short)(p + 1);
    }
    return;
  }

  // ---------------- consumer (wave 0): R6 recurrence ----------------
  const int g     = lane & 3;            // gate: 0=i 1=f 2=g 3=o
  const int j     = (lane >> 2) & 3;     // hidden unit
  const int layer = (lane >> 4) & 1;
  const int b     = b0 + (lane >> 5);

  const float sg = (g == 2) ? 2.f * LOG2E : -LOG2E;
  const float ka = (g == 2) ? -4.f * LOG2E : 1.f;
  const float kb = (g == 2) ?  2.f * LOG2E : 0.f;

  const int row4 = (g * 4 + j) * 4;
  const float* whh = layer ? Whh1 : Whh0;
  float wA[4], wB[4];
#pragma unroll
  for (int m = 0; m < 4; ++m) {          // A_m = h[j^m] (ds_swizzle xor map)
    wA[m] = sg * whh[row4 + (j ^ m)];
    wB[m] = layer ? sg * Wih1[row4 + (j ^ m)] : 0.f;
  }
  const int len = lens[b];

  // base = keep*buf + badd: layer0 takes streamed xg (bias folded in),
  // layer1 takes its constant prescaled bias.
  const float keep = layer ? 0.f : 1.f;
  const float badd = layer ? sg * (bih1[g * 4 + j] + bhh1[g * 4 + j]) : 0.f;

  unsigned ofs = layer ? (unsigned)(WS_XG_F * 4)
                       : (unsigned)(WS_XG_F * 4 + (b * 16 + j * 4 + g) * 4);
  const unsigned stride = layer ? 0u : (unsigned)(BATCH * 16 * 4);
  const unsigned maxofs = (unsigned)(WS_XG_F * 4) + XG_BYTES - 4u;

  float* sp = out + b * 4 + j;           // stored by (layer==1, g==0) lanes

  float A0 = 0.f, A1 = 0.f, A2 = 0.f, A3 = 0.f;
  float B0 = 0.f, B1 = 0.f, B2 = 0.f, B3 = 0.f;
  float cs = 0.f;

  const char* wsr = (const char*)ws;
  auto ld1 = [&](unsigned o) -> float {
    o = (o > maxofs) ? maxofs : o;
    return *(const float*)(wsr + o);
  };

  volatile unsigned long long* pq = &progq;
  int avail = 0;
  auto wait_t = [&](int need) {          // ensure t < need all produced
    if (avail >= need) return;
    for (;;) {
      const unsigned long long v = *pq;  // ds_read_b64, wave-uniform
      unsigned v0 = (unsigned)(v & 0xffff);
      unsigned v1 = (unsigned)((v >> 16) & 0xffff);
      unsigned v2 = (unsigned)((v >> 32) & 0xffff);
      unsigned v3 = (unsigned)((v >> 48) & 0xffff);
      unsigned m01 = v0 < v1 ? v0 : v1;
      unsigned m23 = v2 < v3 ? v2 : v3;
      unsigned mn  = m01 < m23 ? m01 : m23;
      avail = (int)(8u * mn);
      if (avail >= need) break;
      __builtin_amdgcn_s_sleep(8);
    }
    asm volatile("" ::: "memory");       // no hoisting loads above the gate
  };

  auto step = [&](const float bufv, int t, bool do_store) {
    const float base = fmaf(keep, bufv, badd);
    float p0 = fmaf(A0, wA[0], base);
    p0 = fmaf(A1, wA[1], p0);
    float p1 = A2 * wA[2];
    p1 = fmaf(A3, wA[3], p1);
    float p2 = fmaf(B0, wB[0], B1 * wB[1]);
    float p3 = fmaf(B2, wB[2], B3 * wB[3]);
    const float P = (p0 + p1) + (p2 + p3);

    const float r   = rcp_(1.f + ex2_(P));
    const float act = fmaf(ka, r, kb);

    const float vi = dppf<0x00>(act), vf = dppf<0x55>(act),
                vg = dppf<0xAA>(act), vo = dppf<0xFF>(act);

    cs = fmaf(vf, cs, vi * vg);
    const float tc = fmaf(-2.f, rcp_(1.f + ex2_(cs)), 1.f);
    const float hq = vo * tc;

    A0 = hq;
    A1 = swzf<0x101F>(hq);               // lane ^ 4
    A2 = swzf<0x201F>(hq);               // lane ^ 8
    A3 = swzf<0x301F>(hq);               // lane ^ 12
    B0 = swzf<0x401F>(hq);               // lane ^ 16 (layer ship)
    B1 = swzf<0x501F>(hq);               // lane ^ 20
    B2 = swzf<0x601F>(hq);               // lane ^ 24
    B3 = swzf<0x701F>(hq);               // lane ^ 28

    if (do_store) {
      if (layer && g == 0) *sp = (t < len) ? hq : 0.f;
      sp += BATCH * 4;
    }
  };

  // prologue: prefetch t=0..7 (gated), step t=0, reset layer1, load t=8
  wait_t(16);
  float buf[8];
#pragma unroll
  for (int p = 0; p < 8; ++p) { buf[p] = ld1(ofs); ofs += stride; }
  step(buf[0], -1, false);
  if (layer) { cs = 0.f; A0 = 0.f; A1 = 0.f; A2 = 0.f; A3 = 0.f; }
  buf[0] = ld1(ofs); ofs += stride;

  // main: window wi covers k = 8wi+1..8wi+8; loads fetch t = 8wi+9..8wi+16
  // -> gate on avail >= 8wi+24 (next multiple of 8 above 8wi+17), cap LSEQ.
  for (int wi = 0; wi < LSEQ / 8; ++wi) {
    int need = 8 * wi + 24;
    if (need > LSEQ) need = LSEQ;
    wait_t(need);
#pragma unroll
    for (int kk = 0; kk < 8; ++kk) {
      const int k = 8 * wi + 1 + kk;
      step(buf[(1 + kk) & 7], k - 1, true);
      buf[(1 + kk) & 7] = ld1(ofs); ofs += stride;
    }
  }
}

extern "C" void kernel_launch(void* const* d_in, const int* in_sizes, int n_in,
                              void* d_out, int out_size, void* d_ws, size_t ws_size,
                              hipStream_t stream) {
  const float* x    = (const float*)d_in[0];
  const int*   lens = (const int*)d_in[1];
  const float* Wih0 = (const float*)d_in[2];
  const float* Whh0 = (const float*)d_in[3];
  const float* bih0 = (const float*)d_in[4];
  const float* bhh0 = (const float*)d_in[5];
  const float* Wih1 = (const float*)d_in[6];
  const float* Whh1 = (const float*)d_in[7];
  const float* bih1 = (const float*)d_in[8];
  const float* bhh1 = (const float*)d_in[9];
  float* ws  = (float*)d_ws;
  float* out = (float*)d_out;

  lstm_fused<<<BATCH / 2, 320, 0, stream>>>(
      x, lens, Wih0, Whh0, bih0, bhh0, Wih1, Whh1, bih1, bhh1, ws, out);
}

// Round 5
// 812.184 us; speedup vs baseline: 1.2558x; 1.2558x over previous
//
#include <hip/hip_runtime.h>

// 2-layer LSTM (PyTorch gate order i,f,g,o), L=2048, B=512, INPUT=78, H=4.
//
// R10: fused producer-consumer, producers de-pathologized.
//   R9's fused attempt ran 701us because (evidence: VGPR_Count=68 < 78):
//     (1) producer weight row wr[78] went to SCRATCH (re-read every pass),
//     (2) 78 scalar x loads/pass -> 4 TA segments each, 4 waves sharing TA,
//     (3) __threadfence_block (vmcnt(0) drain) EVERY pass.
//   Fixes: __launch_bounds__(320,2) -> 256-VGPR budget, wr2[39] vf2 resident;
//   float2 x loads (rows 8B-aligned: 78*4*idx, 78 even); fence+signal every
//   4 passes. Producer estimate ~180us < consumer 260us -> hidden.
//
//   256 blocks x 320 threads: wave 0 = R6-verified consumer recurrence
//   (16 lanes/(batch,layer), one gate/lane, 4 trans/step, quad_perm gather,
//   7 ds_swizzle XORs, prefetch 8). Waves 1-4 = producers of this block's
//   own xg slice (2 batches x 2048 t x 16 gates); wave w pass p covers
//   t = 8p + 2(w-1) + {0,1}. Handoff block-local (same CU/XCD): stores ->
//   threadfence_block -> LDS u16 watermark; consumer gates 8-step windows on
//   avail = 8*min(watermarks), short-circuits once 2048.
//
// ws: [20480 B, 20480+64MiB) xg0[t][b][j*4+g], prescaled by +-log2e.

#define LSEQ  2048
#define BATCH 512
#define NIN   78
#define LOG2E 1.4426950408889634f

#define WS_XG_F    5120
#define XG_BYTES   ((unsigned)LSEQ * BATCH * 16u * 4u)

typedef __attribute__((ext_vector_type(2))) float vf2;

__device__ __forceinline__ float rcp_(float x) { return __builtin_amdgcn_rcpf(x); }
__device__ __forceinline__ float ex2_(float x) { return __builtin_amdgcn_exp2f(x); }
__device__ __forceinline__ vf2 pkfma(vf2 a, vf2 b, vf2 c) {
  return __builtin_elementwise_fma(a, b, c);
}

template<int CTRL>
__device__ __forceinline__ float dppf(float x) {
  int r = __builtin_amdgcn_update_dpp(0, __builtin_bit_cast(int, x), CTRL, 0xf, 0xf, false);
  return __builtin_bit_cast(float, r);
}
template<int PAT>
__device__ __forceinline__ float swzf(float x) {
  int r = __builtin_amdgcn_ds_swizzle(__builtin_bit_cast(int, x), PAT);
  return __builtin_bit_cast(float, r);
}

__global__ __launch_bounds__(320, 2) void lstm_fused(
    const float* __restrict__ x,
    const int* __restrict__ lens,
    const float* __restrict__ Wih0, const float* __restrict__ Whh0,
    const float* __restrict__ bih0, const float* __restrict__ bhh0,
    const float* __restrict__ Wih1, const float* __restrict__ Whh1,
    const float* __restrict__ bih1, const float* __restrict__ bhh1,
    float* __restrict__ ws, float* __restrict__ out)
{
  __shared__ unsigned long long progq;   // 4 x u16 producer watermarks
  const int tid  = threadIdx.x;
  const int wave = tid >> 6;
  const int lane = tid & 63;
  if (tid == 0) progq = 0ull;
  __syncthreads();                       // only barrier in the kernel
  const int b0 = blockIdx.x * 2;

  if (wave != 0) {
    // ---------------- producers (waves 1..4) ----------------
    const int w   = wave;                // 1..4
    const int a   = lane & 15;           // output index j*4+g
    const int grp = lane >> 4;
    const int dt  = grp >> 1, db = grp & 1;
    const int j   = a >> 2, g = a & 3;
    const float s = (g == 2) ? 2.f * LOG2E : -LOG2E;
    const int row = g * 4 + j;           // PyTorch row = gate*4 + unit

    vf2 wr2[39];                         // prescaled weight row, registers
#pragma unroll
    for (int k2 = 0; k2 < 39; ++k2)
      wr2[k2] = vf2{ s * Wih0[row * NIN + 2 * k2],
                     s * Wih0[row * NIN + 2 * k2 + 1] };
    const float bias0 = s * (bih0[row] + bhh0[row]);

    const int b = b0 + db;
    float* __restrict__ xg = ws + WS_XG_F;
    volatile unsigned short* pr = (volatile unsigned short*)&progq;

    for (int p = 0; p < LSEQ / 8; ++p) {
      const int t = 8 * p + 2 * (w - 1) + dt;
      const vf2* __restrict__ xr2 = (const vf2*)(x + ((size_t)t * BATCH + b) * NIN);
      vf2 acc0 = vf2{ bias0, 0.f }, acc1 = vf2{ 0.f, 0.f };
      vf2 acc2 = vf2{ 0.f, 0.f },  acc3 = vf2{ 0.f, 0.f };
#pragma unroll
      for (int k2 = 0; k2 < 36; k2 += 4) {
        acc0 = pkfma(xr2[k2],     wr2[k2],     acc0);
        acc1 = pkfma(xr2[k2 + 1], wr2[k2 + 1], acc1);
        acc2 = pkfma(xr2[k2 + 2], wr2[k2 + 2], acc2);
        acc3 = pkfma(xr2[k2 + 3], wr2[k2 + 3], acc3);
      }
      acc0 = pkfma(xr2[36], wr2[36], acc0);
      acc1 = pkfma(xr2[37], wr2[37], acc1);
      acc2 = pkfma(xr2[38], wr2[38], acc2);
      const vf2 s2 = (acc0 + acc1) + (acc2 + acc3);
      xg[((size_t)t * BATCH + b) * 16 + a] = s2.x + s2.y;

      if ((p & 3) == 3) {                // fence+signal every 4 passes
        __threadfence_block();
        if (lane == 0) pr[w - 1] = (unsigned short)(p + 1);
      }
    }
    return;
  }

  // ---------------- consumer (wave 0): R6 recurrence (verified) ----------
  const int g     = lane & 3;            // gate: 0=i 1=f 2=g 3=o
  const int j     = (lane >> 2) & 3;     // hidden unit
  const int layer = (lane >> 4) & 1;
  const int b     = b0 + (lane >> 5);

  const float sg = (g == 2) ? 2.f * LOG2E : -LOG2E;
  const float ka = (g == 2) ? -4.f * LOG2E : 1.f;
  const float kb = (g == 2) ?  2.f * LOG2E : 0.f;

  const int row4 = (g * 4 + j) * 4;
  const float* whh = layer ? Whh1 : Whh0;
  float wA[4], wB[4];
#pragma unroll
  for (int m = 0; m < 4; ++m) {          // A_m = h[j^m] (ds_swizzle xor map)
    wA[m] = sg * whh[row4 + (j ^ m)];
    wB[m] = layer ? sg * Wih1[row4 + (j ^ m)] : 0.f;
  }
  const int len = lens[b];

  // base = keep*buf + badd: layer0 takes streamed xg (bias folded in),
  // layer1 takes its constant prescaled bias.
  const float keep = layer ? 0.f : 1.f;
  const float badd = layer ? sg * (bih1[g * 4 + j] + bhh1[g * 4 + j]) : 0.f;

  unsigned ofs = layer ? (unsigned)(WS_XG_F * 4)
                       : (unsigned)(WS_XG_F * 4 + (b * 16 + j * 4 + g) * 4);
  const unsigned stride = layer ? 0u : (unsigned)(BATCH * 16 * 4);
  const unsigned maxofs = (unsigned)(WS_XG_F * 4) + XG_BYTES - 4u;

  float* sp = out + b * 4 + j;           // stored by (layer==1, g==0) lanes

  float A0 = 0.f, A1 = 0.f, A2 = 0.f, A3 = 0.f;
  float B0 = 0.f, B1 = 0.f, B2 = 0.f, B3 = 0.f;
  float cs = 0.f;

  const char* wsr = (const char*)ws;
  auto ld1 = [&](unsigned o) -> float {
    o = (o > maxofs) ? maxofs : o;
    return *(const float*)(wsr + o);
  };

  volatile unsigned long long* pq = &progq;
  int avail = 0;
  auto wait_t = [&](int need) {          // ensure t < need all produced
    if (avail >= need) return;
    for (;;) {
      const unsigned long long v = *pq;  // ds_read_b64, wave-uniform
      unsigned v0 = (unsigned)(v & 0xffff);
      unsigned v1 = (unsigned)((v >> 16) & 0xffff);
      unsigned v2 = (unsigned)((v >> 32) & 0xffff);
      unsigned v3 = (unsigned)((v >> 48) & 0xffff);
      unsigned m01 = v0 < v1 ? v0 : v1;
      unsigned m23 = v2 < v3 ? v2 : v3;
      unsigned mn  = m01 < m23 ? m01 : m23;
      avail = (int)(8u * mn);
      if (avail >= need) break;
      __builtin_amdgcn_s_sleep(8);
    }
    asm volatile("" ::: "memory");       // no hoisting loads above the gate
  };

  auto step = [&](const float bufv, int t, bool do_store) {
    const float base = fmaf(keep, bufv, badd);
    float p0 = fmaf(A0, wA[0], base);
    p0 = fmaf(A1, wA[1], p0);
    float p1 = A2 * wA[2];
    p1 = fmaf(A3, wA[3], p1);
    float p2 = fmaf(B0, wB[0], B1 * wB[1]);
    float p3 = fmaf(B2, wB[2], B3 * wB[3]);
    const float P = (p0 + p1) + (p2 + p3);

    const float r   = rcp_(1.f + ex2_(P));
    const float act = fmaf(ka, r, kb);

    const float vi = dppf<0x00>(act), vf = dppf<0x55>(act),
                vg = dppf<0xAA>(act), vo = dppf<0xFF>(act);

    cs = fmaf(vf, cs, vi * vg);
    const float tc = fmaf(-2.f, rcp_(1.f + ex2_(cs)), 1.f);
    const float hq = vo * tc;

    A0 = hq;
    A1 = swzf<0x101F>(hq);               // lane ^ 4
    A2 = swzf<0x201F>(hq);               // lane ^ 8
    A3 = swzf<0x301F>(hq);               // lane ^ 12
    B0 = swzf<0x401F>(hq);               // lane ^ 16 (layer ship)
    B1 = swzf<0x501F>(hq);               // lane ^ 20
    B2 = swzf<0x601F>(hq);               // lane ^ 24
    B3 = swzf<0x701F>(hq);               // lane ^ 28

    if (do_store) {
      if (layer && g == 0) *sp = (t < len) ? hq : 0.f;
      sp += BATCH * 4;
    }
  };

  // prologue: prefetch t=0..7 (gated), step t=0, reset layer1, load t=8
  wait_t(16);
  float buf[8];
#pragma unroll
  for (int p = 0; p < 8; ++p) { buf[p] = ld1(ofs); ofs += stride; }
  step(buf[0], -1, false);
  if (layer) { cs = 0.f; A0 = 0.f; A1 = 0.f; A2 = 0.f; A3 = 0.f; }
  buf[0] = ld1(ofs); ofs += stride;

  // main: window wi covers k = 8wi+1..8wi+8; loads fetch t = 8wi+9..8wi+16
  // -> gate on avail >= 8wi+24 (next multiple of 8 above 8wi+17), cap LSEQ.
  for (int wi = 0; wi < LSEQ / 8; ++wi) {
    int need = 8 * wi + 24;
    if (need > LSEQ) need = LSEQ;
    wait_t(need);
#pragma unroll
    for (int kk = 0; kk < 8; ++kk) {
      const int k = 8 * wi + 1 + kk;
      step(buf[(1 + kk) & 7], k - 1, true);
      buf[(1 + kk) & 7] = ld1(ofs); ofs += stride;
    }
  }
}

extern "C" void kernel_launch(void* const* d_in, const int* in_sizes, int n_in,
                              void* d_out, int out_size, void* d_ws, size_t ws_size,
                              hipStream_t stream) {
  const float* x    = (const float*)d_in[0];
  const int*   lens = (const int*)d_in[1];
  const float* Wih0 = (const float*)d_in[2];
  const float* Whh0 = (const float*)d_in[3];
  const float* bih0 = (const float*)d_in[4];
  const float* bhh0 = (const float*)d_in[5];
  const float* Wih1 = (const float*)d_in[6];
  const float* Whh1 = (const float*)d_in[7];
  const float* bih1 = (const float*)d_in[8];
  const float* bhh1 = (const float*)d_in[9];
  float* ws  = (float*)d_ws;
  float* out = (float*)d_out;

  lstm_fused<<<BATCH / 2, 320, 0, stream>>>(
      x, lens, Wih0, Whh0, bih0, bhh0, Wih1, Whh1, bih1, bhh1, ws, out);
}